// Round 6
// baseline (640.179 us; speedup 1.0000x reference)
//
#include <hip/hip_runtime.h>

#define N 96
#define NNN (N * N * N)
#define C_CH 32

// tile geometry: block 8x8x4 = 256 threads, each thread computes 4 voxels along w.
// NO LDS, NO BARRIERS: per-channel halo tile (8.4 KB) is L1-resident; each wave
// runs free. Three rounds of counters showed the block-wide barrier pipeline
// parked waves ~75% of each channel step regardless of prefetch depth.
#define TXD 8
#define TYD 8
#define TZD 4
#define VX 4
#define TW (TXD * VX)          // 32
#define TH TYD                 // 8
#define TD TZD                 // 4
#define NTH (TXD * TYD * TZD)  // 256

// native clang vector for nontemporal builtin (HIP float4 is a class type)
typedef float vfloat4 __attribute__((ext_vector_type(4)));

__global__ __launch_bounds__(NTH, 2) void wincorr_kernel(
    const float* __restrict__ fixedp,
    const float* __restrict__ movingp,
    float* __restrict__ outp)
{
    const int tx = threadIdx.x;   // 0..7  (w / 4)
    const int ty = threadIdx.y;   // 0..7  (h)
    const int tz = threadIdx.z;   // 0..3  (d)

    const int w0 = blockIdx.x * TW;
    const int h0 = blockIdx.y * TH;
    const int d0 = blockIdx.z * TD;

    const int gw = w0 + VX * tx;
    const int fix_base = ((d0 + tz) * N + (h0 + ty)) * N + gw;

    // ---- channel-invariant row addresses + masks (branchless boundaries) ----
    // row r = i*3+j covers moving[d0+tz-1+i][h0+ty-1+j][gw-1 .. gw+4].
    // Invalid rows: clamped (always-safe) address + rmf=0 folded into the fixed
    // operand. w edges: clamped scalar address + mwL/mwR multiplicative mask.
    int rowoff[9];
    float rmf[9];
    #pragma unroll
    for (int i = 0; i < 3; ++i) {
        #pragma unroll
        for (int j = 0; j < 3; ++j) {
            const int d = d0 + tz - 1 + i;
            const int h = h0 + ty - 1 + j;
            const bool ok = ((unsigned)d < N) && ((unsigned)h < N);
            const int cd = min(max(d, 0), N - 1);
            const int ch = min(max(h, 0), N - 1);
            rowoff[i * 3 + j] = (cd * N + ch) * N + gw;
            rmf[i * 3 + j] = ok ? 1.0f : 0.0f;
        }
    }
    const int   dL  = (gw > 0) ? -1 : 0;          // left-neighbor offset (clamped)
    const int   dR  = (gw + VX < N) ? VX : VX - 1;// right-neighbor offset (clamped)
    const float mwL = (gw > 0) ? 1.0f : 0.0f;
    const float mwR = (gw + VX < N) ? 1.0f : 0.0f;

    float acc[27][VX];
    #pragma unroll
    for (int s = 0; s < 27; ++s)
        #pragma unroll
        for (int v = 0; v < VX; ++v) acc[s][v] = 0.0f;

    for (int c = 0; c < C_CH; ++c) {
        const float* __restrict__ p = movingp + (size_t)c * NNN;

        // issue all 28 loads for this channel up front (independent, stay in
        // flight; FMAs below consume row-by-row with counted waits)
        float4 A[9];   // w(gw .. gw+3), 16B-aligned
        float  Cv[9];  // w(gw-1)  (clamped at left edge, masked)
        float  Dv[9];  // w(gw+4)  (clamped at right edge, masked)
        #pragma unroll
        for (int r = 0; r < 9; ++r) {
            A[r]  = *(const float4*)(p + rowoff[r]);
            Cv[r] = p[rowoff[r] + dL];
            Dv[r] = p[rowoff[r] + dR];
        }
        const float4 f = *(const float4*)&fixedp[(size_t)c * NNN + fix_base];

        #pragma unroll
        for (int r = 0; r < 9; ++r) {
            const float t0 = f.x * rmf[r];
            const float t1 = f.y * rmf[r];
            const float t2 = f.z * rmf[r];
            const float t3 = f.w * rmf[r];
            const float tL = t0 * mwL;
            const float tR = t3 * mwR;
            const int b = r * 3;
            // k = 0 : taps at w = gw+v-1  -> [Cv, A.x, A.y, A.z]
            acc[b + 0][0] += tL * Cv[r];
            acc[b + 0][1] += t1 * A[r].x;
            acc[b + 0][2] += t2 * A[r].y;
            acc[b + 0][3] += t3 * A[r].z;
            // k = 1 : taps at w = gw+v    -> [A.x, A.y, A.z, A.w]
            acc[b + 1][0] += t0 * A[r].x;
            acc[b + 1][1] += t1 * A[r].y;
            acc[b + 1][2] += t2 * A[r].z;
            acc[b + 1][3] += t3 * A[r].w;
            // k = 2 : taps at w = gw+v+1  -> [A.y, A.z, A.w, Dv]
            acc[b + 2][0] += t0 * A[r].y;
            acc[b + 2][1] += t1 * A[r].z;
            acc[b + 2][2] += t2 * A[r].w;
            acc[b + 2][3] += tR * Dv[r];
        }
    }

    const float scale = 0.17677669529663687f; // 32^-0.5
    #pragma unroll
    for (int s = 0; s < 27; ++s) {
        vfloat4 o;
        o.x = acc[s][0] * scale;
        o.y = acc[s][1] * scale;
        o.z = acc[s][2] * scale;
        o.w = acc[s][3] * scale;
        // write-once output: nontemporal keeps the moving slab resident in L2
        __builtin_nontemporal_store(o, (vfloat4*)&outp[(size_t)s * NNN + fix_base]);
    }
}

extern "C" void kernel_launch(void* const* d_in, const int* in_sizes, int n_in,
                              void* d_out, int out_size, void* d_ws, size_t ws_size,
                              hipStream_t stream) {
    const float* fixedp  = (const float*)d_in[0];
    const float* movingp = (const float*)d_in[1];
    float* outp = (float*)d_out;

    dim3 block(TXD, TYD, TZD);                    // 8 x 8 x 4 = 256
    dim3 grid(N / TW, N / TH, N / TD);            // 3 x 12 x 24 = 864
    wincorr_kernel<<<grid, block, 0, stream>>>(fixedp, movingp, outp);
}

// Round 7
// 362.822 us; speedup vs baseline: 1.7644x; 1.7644x over previous
//
#include <hip/hip_runtime.h>

#define N 96
#define NNN (N * N * N)
#define C_CH 32

// tile 32x8x4 (same as the best 117us kernel -> same FETCH), but computed by a
// 512-thread block at VX=2: acc[27][2]=54 regs -> VGPR<=128 -> 16 waves/CU,
// DOUBLE the TLP of the VX=4 variant (which needed >128 VGPR for acc[27][4]).
#define TXD 16
#define TYD 8
#define TZD 4
#define VX 2
#define TW (TXD * VX)          // 32
#define TH TYD                 // 8
#define TD TZD                 // 4

// halo tile in LDS: 34 x 10 x 6, row padded to 35.
// At VX=2 a wave's lanes read 35*ty + 2*tx (tx 0..15, ty 0..3): each bank is
// hit exactly twice per access -> 2-way = free (m136). (HWS=20 was 4-way.)
#define HWS 35
#define HH 10
#define HD 6
#define PLANE (HWS * HH)       // 350
#define HTOT (PLANE * HD)      // 2100
#define NTH (TXD * TYD * TZD)  // 512
#define NR ((HTOT + NTH - 1) / NTH)  // 5 staging rounds
#define SMSZ (NR * NTH)        // 2560 (over-allocated so stores are unconditional)

// native clang vector for nontemporal builtin (HIP float2 is a class type)
typedef float vfloat2 __attribute__((ext_vector_type(2)));

__global__ __launch_bounds__(NTH, 4) void wincorr_kernel(
    const float* __restrict__ fixedp,
    const float* __restrict__ movingp,
    float* __restrict__ outp)
{
    // LDS double buffer + ONE raw barrier per channel (no vmcnt(0) drain):
    // compute(c) reads buf(c&1) between barriers B_c and B_{c+1}; writes of
    // channel c+2 into buf(c&1) come after B_{c+1} in program order.
    // Branchless staging: unconditional load from CLAMPED offset, 0/1 mask
    // multiplied in at the ds_write (first use of the loaded register is at the
    // consume site -> counted vmcnt; contiguous ds_write addresses -> no
    // bank conflicts; OOB halo words get 0 written every channel).
    __shared__ float smA[SMSZ];
    __shared__ float smB[SMSZ];

    const int tx = threadIdx.x;   // 0..15 (w / 2)
    const int ty = threadIdx.y;   // 0..7  (h)
    const int tz = threadIdx.z;   // 0..3  (d)
    const int tid = tx + TXD * ty + TXD * TYD * tz;

    const int w0 = blockIdx.x * TW;
    const int h0 = blockIdx.y * TH;
    const int d0 = blockIdx.z * TD;

    // ---- channel-invariant staging addresses + masks ----
    int   off[NR];   // global word offset, clamped to 0 when OOB (always loadable)
    float msk[NR];   // 1.0 for valid halo words, 0.0 otherwise
    #pragma unroll
    for (int r = 0; r < NR; ++r) {
        const int a = tid + r * NTH;
        const int z   = a / PLANE;
        const int rm  = a - z * PLANE;
        const int y   = rm / HWS;
        const int x   = rm - y * HWS;
        const int sd = d0 - 1 + z;
        const int sh = h0 - 1 + y;
        const int sw = w0 - 1 + x;
        const bool ok = (a < HTOT) && (x < TW + 2) &&
                        ((unsigned)sd < N) && ((unsigned)sh < N) && ((unsigned)sw < N);
        off[r] = ok ? ((sd * N + sh) * N + sw) : 0;
        msk[r] = ok ? 1.0f : 0.0f;
    }

    const int gw = w0 + VX * tx;
    const int fix_base = ((d0 + tz) * N + (h0 + ty)) * N + gw;
    const int lbase = tz * PLANE + ty * HWS + VX * tx;

    float acc[27][VX];
    #pragma unroll
    for (int s = 0; s < 27; ++s)
        #pragma unroll
        for (int v = 0; v < VX; ++v) acc[s][v] = 0.0f;

    // ---- prologue: depth-2 prefetch (channels 0 and 1 both in flight) ----
    float st0[NR], st1[NR];
    #pragma unroll
    for (int r = 0; r < NR; ++r) st0[r] = movingp[off[r]];
    {
        const float* m1 = movingp + (size_t)NNN;
        #pragma unroll
        for (int r = 0; r < NR; ++r) st1[r] = m1[off[r]];
    }
    float2 f0 = *(const float2*)&fixedp[fix_base];
    float2 f1 = *(const float2*)&fixedp[(size_t)NNN + fix_base];

    auto step = [&](int c, float* __restrict__ smw, float (&st)[NR], float2& f) {
        // commit channel c to LDS — first use of st's registers, so the compiler
        // emits a counted vmcnt here (channel c+1's loads remain outstanding)
        #pragma unroll
        for (int r = 0; r < NR; ++r)
            smw[tid + r * NTH] = st[r] * msk[r];

        // snapshot fixed operand before its registers are reissued
        const float fv0 = f.x, fv1 = f.y;

        // issue channel c+2 into the just-freed register set
        if (c + 2 < C_CH) {
            const float* mn = movingp + (size_t)(c + 2) * NNN;
            #pragma unroll
            for (int r = 0; r < NR; ++r) st[r] = mn[off[r]];
            f = *(const float2*)&fixedp[(size_t)(c + 2) * NNN + fix_base];
        }

        // LDS writes visible, raw barrier — global prefetch survives it
        asm volatile("s_waitcnt lgkmcnt(0)" ::: "memory");
        __builtin_amdgcn_s_barrier();
        asm volatile("" ::: "memory");

        // compute: 9 rows x 4-float sliding window, 27 taps x 2 voxels
        #pragma unroll
        for (int i = 0; i < 3; ++i) {
            #pragma unroll
            for (int j = 0; j < 3; ++j) {
                const float* row = &smw[lbase + i * PLANE + j * HWS];
                float wv[VX + 2];
                #pragma unroll
                for (int m = 0; m < VX + 2; ++m) wv[m] = row[m];
                #pragma unroll
                for (int k = 0; k < 3; ++k) {
                    acc[(i * 3 + j) * 3 + k][0] += fv0 * wv[k];
                    acc[(i * 3 + j) * 3 + k][1] += fv1 * wv[k + 1];
                }
            }
        }
    };

    for (int c = 0; c < C_CH; c += 2) {
        step(c,     smA, st0, f0);
        step(c + 1, smB, st1, f1);
    }

    const float scale = 0.17677669529663687f; // 32^-0.5
    #pragma unroll
    for (int s = 0; s < 27; ++s) {
        vfloat2 o;
        o.x = acc[s][0] * scale;
        o.y = acc[s][1] * scale;
        // write-once output: nontemporal keeps the moving slab resident in L2
        __builtin_nontemporal_store(o, (vfloat2*)&outp[(size_t)s * NNN + fix_base]);
    }
}

extern "C" void kernel_launch(void* const* d_in, const int* in_sizes, int n_in,
                              void* d_out, int out_size, void* d_ws, size_t ws_size,
                              hipStream_t stream) {
    const float* fixedp  = (const float*)d_in[0];
    const float* movingp = (const float*)d_in[1];
    float* outp = (float*)d_out;

    dim3 block(TXD, TYD, TZD);                    // 16 x 8 x 4 = 512
    dim3 grid(N / TW, N / TH, N / TD);            // 3 x 12 x 24 = 864
    wincorr_kernel<<<grid, block, 0, stream>>>(fixedp, movingp, outp);
}

// Round 8
// 327.420 us; speedup vs baseline: 1.9552x; 1.1081x over previous
//
#include <hip/hip_runtime.h>

#define N 96
#define NNN (N * N * N)
#define C_CH 32

// PER-WAVE PRIVATE TILES — ZERO BARRIERS.
// Each wave owns a 16(w)x4(h)x4(d) voxel tile (VX=4: lane = lx(4) x ly(4) x lz(4),
// each lane computes 4 w-consecutive voxels). The wave stages its own halo
// (18x6x6, row-padded to 19 -> 684 words) into a private LDS slice; write->read
// ordering is intra-wave (compiler-counted lgkmcnt), so NO s_barrier and NO
// vmcnt(0) drain exist anywhere in the channel loop. Block = 4 waves covering
// 32x8x4, grid unchanged -> same output-store pattern as the 117us kernel.
// History: block-wide barrier variants all 117-130us (waves parked at every
// convergence); no-LDS variant 482us (28 VMEM instr/thread/ch). This keeps the
// VMEM count at 11-12 and deletes the convergence.
#define HWS 19
#define HPLANE (HWS * 6)      // 114
#define HTOT (HPLANE * 6)     // 684
#define NR 11                 // ceil(684/64)
#define WBUF (NR * 64)        // 704 (over-allocated; pad words get 0 via mask)
#define NTH 256

// native clang vector for nontemporal builtin (HIP float4 is a class type)
typedef float vfloat4 __attribute__((ext_vector_type(4)));

__global__ __launch_bounds__(NTH, 2) void wincorr_kernel(
    const float* __restrict__ fixedp,
    const float* __restrict__ movingp,
    float* __restrict__ outp)
{
    // [wave][double-buffer][words] : 4 * 2 * 704 * 4B = 22528 B per block
    __shared__ float sm[4][2][WBUF];

    const int tid  = threadIdx.x;
    const int lane = tid & 63;
    const int wid  = tid >> 6;
    const int lx = lane & 3;          // w-quad index (voxel w = 4*lx .. 4*lx+3)
    const int ly = (lane >> 2) & 3;   // h
    const int lz = lane >> 4;         // d

    // wave voxel-tile origin
    const int w0 = blockIdx.x * 32 + (wid & 1) * 16;
    const int h0 = blockIdx.y * 8  + (wid >> 1) * 4;
    const int d0 = blockIdx.z * 4;

    // ---- channel-invariant staging addresses + masks (branchless) ----
    // word a of the wave's halo box: z = a/114, y = (a%114)/19, x = a%19.
    // x==18 is the pad column (never read via taps: max read x = 4*3+5 = 17).
    int   off[NR];
    float msk[NR];
    #pragma unroll
    for (int r = 0; r < NR; ++r) {
        const int a  = lane + 64 * r;
        const int z  = a / HPLANE;
        const int rm = a - z * HPLANE;
        const int y  = rm / HWS;
        const int x  = rm - y * HWS;
        const int sd = d0 - 1 + z;
        const int sh = h0 - 1 + y;
        const int sw = w0 - 1 + x;
        const bool ok = (a < HTOT) && (x < 18) &&
                        ((unsigned)sd < N) && ((unsigned)sh < N) && ((unsigned)sw < N);
        off[r] = ok ? ((sd * N + sh) * N + sw) : 0;
        msk[r] = ok ? 1.0f : 0.0f;
    }

    const int fix_base = ((d0 + lz) * N + (h0 + ly)) * N + (w0 + 4 * lx);
    const int lbase = lz * HPLANE + ly * HWS + 4 * lx;   // halo word of voxel0 - (1,1,1) tap start

    float* const myA = &sm[wid][0][0];
    float* const myB = &sm[wid][1][0];

    float acc[27][4];
    #pragma unroll
    for (int s = 0; s < 27; ++s)
        #pragma unroll
        for (int v = 0; v < 4; ++v) acc[s][v] = 0.0f;

    // ---- prologue: depth-2 register prefetch (channels 0 and 1 in flight) ----
    float st0[NR], st1[NR];
    #pragma unroll
    for (int r = 0; r < NR; ++r) st0[r] = movingp[off[r]];
    {
        const float* m1 = movingp + (size_t)NNN;
        #pragma unroll
        for (int r = 0; r < NR; ++r) st1[r] = m1[off[r]];
    }
    float4 f0 = *(const float4*)&fixedp[fix_base];
    float4 f1 = *(const float4*)&fixedp[(size_t)NNN + fix_base];

    auto step = [&](int c, float* __restrict__ smw, float (&st)[NR], float4& f) {
        // commit channel c (first use of st's registers -> counted vmcnt here;
        // the other register set's loads stay outstanding)
        #pragma unroll
        for (int r = 0; r < NR; ++r)
            smw[lane + 64 * r] = st[r] * msk[r];

        const float fv[4] = {f.x, f.y, f.z, f.w};

        // issue channel c+2 into the just-freed register set
        if (c + 2 < C_CH) {
            const float* mn = movingp + (size_t)(c + 2) * NNN;
            #pragma unroll
            for (int r = 0; r < NR; ++r) st[r] = mn[off[r]];
            f = *(const float4*)&fixedp[(size_t)(c + 2) * NNN + fix_base];
        }

        // NO barrier: same-wave ds_write -> ds_read ordering via lgkmcnt only.

        // compute: 9 rows x 6-float sliding window, 27 taps x 4 voxels
        #pragma unroll
        for (int i = 0; i < 3; ++i) {
            #pragma unroll
            for (int j = 0; j < 3; ++j) {
                const float* row = &smw[lbase + i * HPLANE + j * HWS];
                float wv[6];
                #pragma unroll
                for (int m = 0; m < 6; ++m) wv[m] = row[m];
                #pragma unroll
                for (int k = 0; k < 3; ++k)
                    #pragma unroll
                    for (int v = 0; v < 4; ++v)
                        acc[(i * 3 + j) * 3 + k][v] += fv[v] * wv[v + k];
            }
        }
    };

    for (int c = 0; c < C_CH; c += 2) {
        step(c,     myA, st0, f0);
        step(c + 1, myB, st1, f1);
    }

    const float scale = 0.17677669529663687f; // 32^-0.5
    #pragma unroll
    for (int s = 0; s < 27; ++s) {
        vfloat4 o;
        o.x = acc[s][0] * scale;
        o.y = acc[s][1] * scale;
        o.z = acc[s][2] * scale;
        o.w = acc[s][3] * scale;
        // write-once output: nontemporal keeps the moving slab resident in L2
        __builtin_nontemporal_store(o, (vfloat4*)&outp[(size_t)s * NNN + fix_base]);
    }
}

extern "C" void kernel_launch(void* const* d_in, const int* in_sizes, int n_in,
                              void* d_out, int out_size, void* d_ws, size_t ws_size,
                              hipStream_t stream) {
    const float* fixedp  = (const float*)d_in[0];
    const float* movingp = (const float*)d_in[1];
    float* outp = (float*)d_out;

    dim3 block(NTH, 1, 1);                        // 256 = 4 waves
    dim3 grid(N / 32, N / 8, N / 4);              // 3 x 12 x 24 = 864
    wincorr_kernel<<<grid, block, 0, stream>>>(fixedp, movingp, outp);
}

// Round 9
// 282.846 us; speedup vs baseline: 2.2633x; 1.1576x over previous
//
#include <hip/hip_runtime.h>

#define N 96
#define NNN (N * N * N)
#define C_CH 32

// tile geometry: block 8x8x4 = 256 threads, each thread computes 4 voxels along w.
// This exact geometry (tile 32x8x4, NR=9) is the only one that fits the
// register budget (acc[27][4]=108 + staging pipeline < 128 VGPR). All other
// geometries tried (VX=2, 512-thread, per-wave) spilled or conflicted.
#define TXD 8
#define TYD 8
#define TZD 4
#define VX 4
#define TW (TXD * VX)          // 32
#define TH TYD                 // 8
#define TD TZD                 // 4

// halo tile in LDS: 34 x 10 x 6, row padded to 36 (EVEN, mult of 4):
// every window-read base is ==0 mod 4 words -> 16B-aligned ds_read_b128 +
// 8B-aligned ds_read_b64 per row (2 instrs) instead of 6x ds_read_b32.
// Lane word-addrs spread evenly over banks (4tx + 4ty + 8tz mod 32).
#define HWS 36
#define HH 10
#define HD 6
#define PLANE (HWS * HH)       // 360
#define HTOT (PLANE * HD)      // 2160
#define NTH (TXD * TYD * TZD)  // 256
#define NR ((HTOT + NTH - 1) / NTH)  // 9 staging rounds
#define SMSZ (NR * NTH)        // 2304 (over-allocated; pads get 0 via mask)

// native clang vector for nontemporal builtin (HIP float4 is a class type)
typedef float vfloat4 __attribute__((ext_vector_type(4)));

__global__ __launch_bounds__(NTH, 2) void wincorr_kernel(
    const float* __restrict__ fixedp,
    const float* __restrict__ movingp,
    float* __restrict__ outp)
{
    // LDS double buffer + ONE raw barrier per channel (no vmcnt(0) drain).
    // BRANCHLESS MASKED STAGING: unconditional load from CLAMPED offset; the
    // 0/1 mask is multiplied in at the ds_write. First use of the loaded
    // register is the ds_write -> compiler emits a COUNTED vmcnt there, so the
    // depth-2 prefetch stays in flight across the barrier (T4 idiom).
    alignas(16) __shared__ float smA[SMSZ];
    alignas(16) __shared__ float smB[SMSZ];

    const int tx = threadIdx.x;   // 0..7  (w / 4)
    const int ty = threadIdx.y;   // 0..7  (h)
    const int tz = threadIdx.z;   // 0..3  (d)
    const int tid = tx + TXD * ty + TXD * TYD * tz;

    const int w0 = blockIdx.x * TW;
    const int h0 = blockIdx.y * TH;
    const int d0 = blockIdx.z * TD;

    // ---- channel-invariant staging addresses + masks ----
    int   off[NR];   // global word offset, clamped to 0 when OOB (always loadable)
    float msk[NR];   // 1.0 for valid halo words, 0.0 otherwise
    #pragma unroll
    for (int r = 0; r < NR; ++r) {
        const int a  = tid + r * NTH;
        const int z  = a / PLANE;
        const int rm = a - z * PLANE;
        const int y  = rm / HWS;
        const int x  = rm - y * HWS;
        const int sd = d0 - 1 + z;
        const int sh = h0 - 1 + y;
        const int sw = w0 - 1 + x;
        const bool ok = (a < HTOT) && (x < 34) &&
                        ((unsigned)sd < N) && ((unsigned)sh < N) && ((unsigned)sw < N);
        off[r] = ok ? ((sd * N + sh) * N + sw) : 0;
        msk[r] = ok ? 1.0f : 0.0f;
    }

    const int gw = w0 + VX * tx;
    const int fix_base = ((d0 + tz) * N + (h0 + ty)) * N + gw;
    // all terms multiples of 4 -> window reads are 16B/8B aligned in LDS
    const int lbase = tz * PLANE + ty * HWS + VX * tx;

    float acc[27][VX];
    #pragma unroll
    for (int s = 0; s < 27; ++s)
        #pragma unroll
        for (int v = 0; v < VX; ++v) acc[s][v] = 0.0f;

    // ---- prologue: depth-2 prefetch (channels 0 and 1 both in flight) ----
    float st0[NR], st1[NR];
    #pragma unroll
    for (int r = 0; r < NR; ++r) st0[r] = movingp[off[r]];
    {
        const float* m1 = movingp + (size_t)NNN;
        #pragma unroll
        for (int r = 0; r < NR; ++r) st1[r] = m1[off[r]];
    }
    float4 f0 = *(const float4*)&fixedp[fix_base];
    float4 f1 = *(const float4*)&fixedp[(size_t)NNN + fix_base];

    auto step = [&](int c, float* __restrict__ smw, float (&st)[NR], float4& f) {
        // commit channel c to LDS — first (and only) use of st's registers, so
        // the counted vmcnt lands here; the other set's loads stay outstanding
        #pragma unroll
        for (int r = 0; r < NR; ++r)
            smw[tid + r * NTH] = st[r] * msk[r];

        // snapshot fixed operand before its registers are reissued
        const float fv[VX] = {f.x, f.y, f.z, f.w};

        // issue channel c+2 into the just-freed register set (clean loads: no
        // selects, no mask ops -> nothing waits at the issue site)
        if (c + 2 < C_CH) {
            const float* mn = movingp + (size_t)(c + 2) * NNN;
            #pragma unroll
            for (int r = 0; r < NR; ++r) st[r] = mn[off[r]];
            f = *(const float4*)&fixedp[(size_t)(c + 2) * NNN + fix_base];
        }

        // LDS writes visible, raw barrier — global prefetch survives it
        asm volatile("s_waitcnt lgkmcnt(0)" ::: "memory");
        __builtin_amdgcn_s_barrier();
        asm volatile("" ::: "memory");

        // compute: 9 rows; per row ONE b128 + ONE b64 read cover the 6-word
        // window [4tx, 4tx+6) = taps (gw-1 .. gw+4)
        #pragma unroll
        for (int i = 0; i < 3; ++i) {
            #pragma unroll
            for (int j = 0; j < 3; ++j) {
                const float* row = &smw[lbase + i * PLANE + j * HWS];
                const float4 q = *(const float4*)row;        // 16B aligned
                const float2 e = *(const float2*)(row + 4);  // 8B aligned
                const float wv[6] = {q.x, q.y, q.z, q.w, e.x, e.y};
                #pragma unroll
                for (int k = 0; k < 3; ++k)
                    #pragma unroll
                    for (int v = 0; v < VX; ++v)
                        acc[(i * 3 + j) * 3 + k][v] += fv[v] * wv[v + k];
            }
        }
    };

    for (int c = 0; c < C_CH; c += 2) {
        step(c,     smA, st0, f0);
        step(c + 1, smB, st1, f1);
    }

    const float scale = 0.17677669529663687f; // 32^-0.5
    #pragma unroll
    for (int s = 0; s < 27; ++s) {
        vfloat4 o;
        o.x = acc[s][0] * scale;
        o.y = acc[s][1] * scale;
        o.z = acc[s][2] * scale;
        o.w = acc[s][3] * scale;
        // write-once output: nontemporal keeps the moving slab resident in L2
        __builtin_nontemporal_store(o, (vfloat4*)&outp[(size_t)s * NNN + fix_base]);
    }
}

extern "C" void kernel_launch(void* const* d_in, const int* in_sizes, int n_in,
                              void* d_out, int out_size, void* d_ws, size_t ws_size,
                              hipStream_t stream) {
    const float* fixedp  = (const float*)d_in[0];
    const float* movingp = (const float*)d_in[1];
    float* outp = (float*)d_out;

    dim3 block(TXD, TYD, TZD);                    // 8 x 8 x 4 = 256
    dim3 grid(N / TW, N / TH, N / TD);            // 3 x 12 x 24 = 864
    wincorr_kernel<<<grid, block, 0, stream>>>(fixedp, movingp, outp);
}